// Round 5
// baseline (808.986 us; speedup 1.0000x reference)
//
#include <hip/hip_runtime.h>

#define N_PTS 20000
#define KNN   16
#define DIMF  256
#define AD    128
#define MD    2500
#define EPSV  1e-5f
#define INV_SCALE 0.08838834764831845f
#define NEG_BIG -3.402823466e38f

// canary: if the whole pipeline runs, proj overwrites this.
__global__ void EventAttention_54382875902362_kernel(float* out) {
  if (threadIdx.x == 0 && blockIdx.x == 0) out[0] = 8192.0f;
}

// ---------------- QKV GEMM (local + global), grid 7500 x 128 ----------------
// bid%6: 0..2 -> local col-block, 3..5 -> global col-block. bid/6 -> row tile.
__global__ void qkv_kernel(const float* feat,
                           const float* wl, const float* bl,
                           const float* wg, const float* bg,
                           float* qkv_l, float* qkv_g)
{
  __shared__ float fs[16][DIMF];
  const int tid  = threadIdx.x;
  const int bid  = blockIdx.x;
  const int row0 = (bid / 6) * 16;
  const int y    = bid % 6;
  for (int t = tid; t < 16 * DIMF; t += 128) {
    int r = t >> 8, c = t & 255;
    fs[r][c] = feat[(size_t)(row0 + r) * DIMF + c];
  }
  __syncthreads();
  const float* w = (y < 3) ? wl : wg;
  const float* b = (y < 3) ? bl : bg;
  float* outp    = (y < 3) ? qkv_l : qkv_g;
  const int col = ((y < 3) ? y : (y - 3)) * 128 + tid;
  float acc0 = 0.f, acc1 = 0.f, acc2 = 0.f, acc3 = 0.f;
  float acc4 = 0.f, acc5 = 0.f, acc6 = 0.f, acc7 = 0.f;
  float acc8 = 0.f, acc9 = 0.f, acc10 = 0.f, acc11 = 0.f;
  float acc12 = 0.f, acc13 = 0.f, acc14 = 0.f, acc15 = 0.f;
  for (int k = 0; k < DIMF; ++k) {
    float wv = w[(size_t)k * 384 + col];
    acc0  = fmaf(fs[0][k],  wv, acc0);
    acc1  = fmaf(fs[1][k],  wv, acc1);
    acc2  = fmaf(fs[2][k],  wv, acc2);
    acc3  = fmaf(fs[3][k],  wv, acc3);
    acc4  = fmaf(fs[4][k],  wv, acc4);
    acc5  = fmaf(fs[5][k],  wv, acc5);
    acc6  = fmaf(fs[6][k],  wv, acc6);
    acc7  = fmaf(fs[7][k],  wv, acc7);
    acc8  = fmaf(fs[8][k],  wv, acc8);
    acc9  = fmaf(fs[9][k],  wv, acc9);
    acc10 = fmaf(fs[10][k], wv, acc10);
    acc11 = fmaf(fs[11][k], wv, acc11);
    acc12 = fmaf(fs[12][k], wv, acc12);
    acc13 = fmaf(fs[13][k], wv, acc13);
    acc14 = fmaf(fs[14][k], wv, acc14);
    acc15 = fmaf(fs[15][k], wv, acc15);
  }
  const float bv = b[col];
  outp[(size_t)(row0 + 0)  * 384 + col] = acc0  + bv;
  outp[(size_t)(row0 + 1)  * 384 + col] = acc1  + bv;
  outp[(size_t)(row0 + 2)  * 384 + col] = acc2  + bv;
  outp[(size_t)(row0 + 3)  * 384 + col] = acc3  + bv;
  outp[(size_t)(row0 + 4)  * 384 + col] = acc4  + bv;
  outp[(size_t)(row0 + 5)  * 384 + col] = acc5  + bv;
  outp[(size_t)(row0 + 6)  * 384 + col] = acc6  + bv;
  outp[(size_t)(row0 + 7)  * 384 + col] = acc7  + bv;
  outp[(size_t)(row0 + 8)  * 384 + col] = acc8  + bv;
  outp[(size_t)(row0 + 9)  * 384 + col] = acc9  + bv;
  outp[(size_t)(row0 + 10) * 384 + col] = acc10 + bv;
  outp[(size_t)(row0 + 11) * 384 + col] = acc11 + bv;
  outp[(size_t)(row0 + 12) * 384 + col] = acc12 + bv;
  outp[(size_t)(row0 + 13) * 384 + col] = acc13 + bv;
  outp[(size_t)(row0 + 14) * 384 + col] = acc14 + bv;
  outp[(size_t)(row0 + 15) * 384 + col] = acc15 + bv;
}

// ---------------- kmax/vmax pooling: grid MD x 128 --------------------------
__global__ void kvmax_kernel(const float* qkv_g, const int* pair_idx,
                             float* kmax, float* vmax)
{
  const int m = blockIdx.x, a = threadIdx.x;
  float km = NEG_BIG, vm = NEG_BIG;
  for (int j = 0; j < KNN; ++j) {
    int p = pair_idx[m * KNN + j];
    km = fmaxf(km, qkv_g[(size_t)p * 384 + 128 + a]);
    vm = fmaxf(vm, qkv_g[(size_t)p * 384 + 256 + a]);
  }
  kmax[m * AD + a] = km;
  vmax[m * AD + a] = vm;
}

// ---------------- per-point attention: grid N x 128 -------------------------
// use_remap=0: neighbor events = events[id]   (local branch)
// use_remap=1: neighbor events = events[remap[id]]  (global branch, remap=down_idx)
__global__ void attn_kernel(const float* events,
                            const int* idx, const int* remap, int use_remap,
                            const float* q_tab, int qs,
                            const float* k_tab, int ks,
                            const float* v_tab, int vs,
                            const float* w1, const float* b1,
                            const float* w2, const float* b2,
                            const float* g,  const float* bb,
                            float* out, int out_off)
{
  __shared__ float hS[KNN][AD];     // relu(d @ w1 + b1), then reused for LN input
  __shared__ float dS[KNN][4];
  __shared__ int   idxS[KNN];
  __shared__ float part[KNN][8][2]; // LN partial sums
  __shared__ float stats[KNN][2];   // mu, rsqrt(var+eps)

  const int n = blockIdx.x;
  const int a = threadIdx.x;

  if (a < KNN * 4) {
    int j = a >> 2, c = a & 3;
    int id = idx[n * KNN + j];
    if (c == 0) idxS[j] = id;
    int erow = use_remap ? remap[id] : id;
    dS[j][c] = events[(size_t)n * 4 + c] - events[(size_t)erow * 4 + c];
  }
  float w1r0 = w1[0 * AD + a];
  float w1r1 = w1[1 * AD + a];
  float w1r2 = w1[2 * AD + a];
  float w1r3 = w1[3 * AD + a];
  const float b1r = b1[a];
  const float b2r = b2[a];
  __syncthreads();

  // layer 1
  for (int j = 0; j < KNN; ++j) {
    float h = b1r;
    h = fmaf(dS[j][0], w1r0, h);
    h = fmaf(dS[j][1], w1r1, h);
    h = fmaf(dS[j][2], w1r2, h);
    h = fmaf(dS[j][3], w1r3, h);
    hS[j][a] = fmaxf(h, 0.f);
  }
  __syncthreads();

  // layer 2: pe[j] = b2[a] + sum_i hS[j][i] * w2[i*AD + a]
  float pe[KNN];
  for (int j = 0; j < KNN; ++j) pe[j] = b2r;
  for (int i = 0; i < AD; ++i) {
    float wv = w2[i * AD + a];
    for (int j = 0; j < KNN; ++j)
      pe[j] = fmaf(hS[j][i], wv, pe[j]);
  }
  // RACE FIX: all threads must finish READING hS (pe loop above) before any
  // thread overwrites it as the LN staging buffer below. Wave 1 finishing
  // early and rewriting hS[j][64..127] corrupted wave 0's pe accumulation.
  __syncthreads();

  // x = q - kg + pe; stash in LDS (reuse hS) for the LN reduction
  const float qv = q_tab[(size_t)n * qs + a];
  float x[KNN];
  for (int j = 0; j < KNN; ++j) {
    int id = idxS[j];
    float kg = k_tab[(size_t)id * ks + a];
    float xv = qv - kg + pe[j];
    x[j] = xv;
    hS[j][a] = xv;
  }
  __syncthreads();

  // LN stats: 8 threads per j, 16 channels each, then combine
  {
    int j = a >> 3;          // 0..15
    int p = a & 7;           // 0..7
    float s1 = 0.f, s2 = 0.f;
    int c0 = p * 16;
    for (int c = c0; c < c0 + 16; ++c) {
      float v = hS[j][c];
      s1 += v;
      s2 += v * v;
    }
    part[j][p][0] = s1;
    part[j][p][1] = s2;
  }
  __syncthreads();
  if (a < KNN) {
    float S1 = 0.f, S2 = 0.f;
    for (int p = 0; p < 8; ++p) {
      S1 += part[a][p][0];
      S2 += part[a][p][1];
    }
    float mu  = S1 * (1.f / AD);
    float var = S2 * (1.f / AD) - mu * mu;
    stats[a][0] = mu;
    stats[a][1] = rsqrtf(var + EPSV);
  }
  __syncthreads();

  const float gr = g[a], br = bb[a];
  float mx = NEG_BIG;
  for (int j = 0; j < KNN; ++j) {
    float s = ((x[j] - stats[j][0]) * stats[j][1] * gr + br) * INV_SCALE;
    x[j] = s;
    mx = fmaxf(mx, s);
  }
  float sum = 0.f;
  for (int j = 0; j < KNN; ++j) {
    float p = expf(x[j] - mx);
    x[j] = p;
    sum += p;
  }
  const float inv = 1.f / sum;
  float o = 0.f;
  for (int j = 0; j < KNN; ++j) {
    int id = idxS[j];
    float vg = v_tab[(size_t)id * vs + a];
    o += x[j] * (vg + pe[j]);
  }
  out[(size_t)n * 256 + out_off + a] = o * inv;
}

// ---------------- proj MLP: grid 1250 x 256 ---------------------------------
__global__ void proj_kernel(const float* attn_cat,
                            const float* w1, const float* b1,
                            const float* w2, const float* b2,
                            float* outp)
{
  __shared__ float inS[16][256];
  __shared__ float hT[16][256];
  const int col  = threadIdx.x;
  const int row0 = blockIdx.x * 16;
  for (int t = col; t < 16 * 256; t += 256) {
    int r = t >> 8, c = t & 255;
    inS[r][c] = attn_cat[(size_t)(row0 + r) * 256 + c];
  }
  __syncthreads();
  float acc[16];
  for (int r = 0; r < 16; ++r) acc[r] = 0.f;
  for (int k = 0; k < 256; ++k) {
    float wv = w1[k * 256 + col];
    for (int r = 0; r < 16; ++r)
      acc[r] = fmaf(inS[r][k], wv, acc[r]);
  }
  const float bv1 = b1[col];
  for (int r = 0; r < 16; ++r) hT[r][col] = fmaxf(acc[r] + bv1, 0.f);
  __syncthreads();
  for (int r = 0; r < 16; ++r) acc[r] = 0.f;
  for (int k = 0; k < 256; ++k) {
    float wv = w2[k * 256 + col];
    for (int r = 0; r < 16; ++r)
      acc[r] = fmaf(hT[r][k], wv, acc[r]);
  }
  const float bv2 = b2[col];
  for (int r = 0; r < 16; ++r)
    outp[(size_t)(row0 + r) * 256 + col] = acc[r] + bv2;
}

// ---------------- launch ----------------------------------------------------
extern "C" void kernel_launch(void* const* d_in, const int* in_sizes, int n_in,
                              void* d_out, int out_size, void* d_ws, size_t ws_size,
                              hipStream_t stream)
{
  const float* events   = (const float*)d_in[0];
  const float* features = (const float*)d_in[1];
  const int* local_idx    = (const int*)d_in[2];
  const int* down_idx     = (const int*)d_in[3];
  const int* pair_idx     = (const int*)d_in[4];
  const int* inv_pair_idx = (const int*)d_in[5];
  const float* l_qkv_w = (const float*)d_in[6];
  const float* l_qkv_b = (const float*)d_in[7];
  const float* l_pe_w1 = (const float*)d_in[8];
  const float* l_pe_b1 = (const float*)d_in[9];
  const float* l_pe_w2 = (const float*)d_in[10];
  const float* l_pe_b2 = (const float*)d_in[11];
  const float* l_fc_g  = (const float*)d_in[12];
  const float* l_fc_b  = (const float*)d_in[13];
  const float* g_qkv_w = (const float*)d_in[14];
  const float* g_qkv_b = (const float*)d_in[15];
  const float* g_pe_w1 = (const float*)d_in[16];
  const float* g_pe_b1 = (const float*)d_in[17];
  const float* g_pe_w2 = (const float*)d_in[18];
  const float* g_pe_b2 = (const float*)d_in[19];
  const float* g_fc_g  = (const float*)d_in[20];
  const float* g_fc_b  = (const float*)d_in[21];
  const float* p_w1 = (const float*)d_in[22];
  const float* p_b1 = (const float*)d_in[23];
  const float* p_w2 = (const float*)d_in[24];
  const float* p_b2 = (const float*)d_in[25];
  (void)in_sizes; (void)n_in; (void)out_size; (void)ws_size;

  // workspace layout (f32)
  char* ws = (char*)d_ws;
  float* qkv_l    = (float*)(ws);                                  // 30.72 MB
  float* qkv_g    = (float*)(ws + (size_t)N_PTS * 384 * 4);        // 30.72 MB
  float* kmax     = (float*)(ws + (size_t)N_PTS * 384 * 8);        // 1.28 MB
  float* vmax     = (float*)(ws + (size_t)N_PTS * 384 * 8 + (size_t)MD * AD * 4);
  float* attn_cat = (float*)(ws + (size_t)N_PTS * 384 * 8 + (size_t)MD * AD * 8);

  EventAttention_54382875902362_kernel<<<1, 64, 0, stream>>>((float*)d_out);
  qkv_kernel<<<(N_PTS / 16) * 6, 128, 0, stream>>>(
      features, l_qkv_w, l_qkv_b, g_qkv_w, g_qkv_b, qkv_l, qkv_g);
  kvmax_kernel<<<MD, 128, 0, stream>>>(qkv_g, pair_idx, kmax, vmax);
  attn_kernel<<<N_PTS, 128, 0, stream>>>(
      events, local_idx, down_idx, 0,
      qkv_l + 0, 384, qkv_l + 128, 384, qkv_l + 256, 384,
      l_pe_w1, l_pe_b1, l_pe_w2, l_pe_b2, l_fc_g, l_fc_b,
      attn_cat, 0);
  attn_kernel<<<N_PTS, 128, 0, stream>>>(
      events, inv_pair_idx, down_idx, 1,
      qkv_g + 0, 384, kmax, 128, vmax, 128,
      g_pe_w1, g_pe_b1, g_pe_w2, g_pe_b2, g_fc_g, g_fc_b,
      attn_cat, 128);
  proj_kernel<<<N_PTS / 16, 256, 0, stream>>>(
      attn_cat, p_w1, p_b1, p_w2, p_b2, (float*)d_out);
}